// Round 1
// baseline (316.017 us; speedup 1.0000x reference)
//
#include <hip/hip_runtime.h>
#include <hip/hip_bf16.h>

#define LN_EPS 1e-5f
#define SLOPE 0.01f

typedef short bf16x8 __attribute__((ext_vector_type(8)));
typedef float f32x4 __attribute__((ext_vector_type(4)));

// ---------------------------------------------------------------------------
// Kernel 1: U[i,d] = robot[i]@W1[0:256] + lang@W1[256:320]
//           V[j,d] = object[j]@W1[320:576] + lang@W1[576:640] + b1[d]
// ---------------------------------------------------------------------------
__global__ __launch_bounds__(320) void precompute_uv(
    const float* __restrict__ robot, const float* __restrict__ object,
    const float* __restrict__ lang, const float* __restrict__ W1,
    const float* __restrict__ b1, float* __restrict__ U, float* __restrict__ V)
{
  const int i = blockIdx.x;   // 0..511
  const int d = threadIdx.x;  // 0..319
  float accU = 0.f, accV = 0.f;
  for (int k = 0; k < 256; ++k) {
    accU = fmaf(robot[i * 256 + k],  W1[k * 320 + d], accU);
    accV = fmaf(object[i * 256 + k], W1[(320 + k) * 320 + d], accV);
  }
  for (int l = 0; l < 64; ++l) {
    const float lv = lang[l];
    accU = fmaf(lv, W1[(256 + l) * 320 + d], accU);
    accV = fmaf(lv, W1[(576 + l) * 320 + d], accV);
  }
  U[i * 320 + d] = accU;
  V[i * 320 + d] = accV + b1[d];
}

// ---------------------------------------------------------------------------
// Kernel 2: W2T[d][k] = bf16(W2[k][d])   (N x K row-major, bf16)
// ---------------------------------------------------------------------------
__global__ __launch_bounds__(320) void transpose_w2(
    const float* __restrict__ W2, __hip_bfloat16* __restrict__ W2T)
{
  const int d = blockIdx.x;   // output row (col of W2)
  const int k = threadIdx.x;  // 0..319
  W2T[d * 320 + k] = __float2bfloat16(W2[k * 320 + d]);
}

// ---------------------------------------------------------------------------
// Kernel 3: fused  LN1 -> leaky -> GEMM2(MFMA bf16) -> LN2 -> leaky -> dot W3
// block = 256 thr (4 waves). block owns (i, j0..j0+63). wave w owns cols
// [w*80, w*80+80) of the 64x320 h2 tile.
// ---------------------------------------------------------------------------
__global__ __launch_bounds__(256) void fused_main(
    const float* __restrict__ U, const float* __restrict__ V,
    const __hip_bfloat16* __restrict__ W2T,
    const float* __restrict__ g1, const float* __restrict__ be1,
    const float* __restrict__ b2, const float* __restrict__ g2,
    const float* __restrict__ be2, const float* __restrict__ W3,
    const float* __restrict__ b3, float* __restrict__ out)
{
  __shared__ __hip_bfloat16 h1[64][328];   // +8 bf16 pad breaks bank alias
  __shared__ float part[64][4][2];         // per-row {sum, sumsq} per wave
  __shared__ float pdot[64][4];            // per-row dot partial per wave

  const int i   = blockIdx.x;        // 0..511
  const int j0  = blockIdx.y * 64;   // j tile base
  const int tid = threadIdx.x;
  const int lane = tid & 63;
  const int w    = tid >> 6;         // wave 0..3
  const int r16  = lane & 15;
  const int g    = lane >> 4;

  const float* __restrict__ Urow = U + i * 320;

  // ---- Phase 1: LN1 + leaky -> h1 (bf16, LDS). wave w does pairs w*16..+15
  for (int q = 0; q < 16; ++q) {
    const int p = w * 16 + q;
    const float* __restrict__ Vrow = V + (j0 + p) * 320;
    float x[5];
    float s = 0.f, ss = 0.f;
#pragma unroll
    for (int t = 0; t < 5; ++t) {
      const int d = lane + t * 64;
      x[t] = Urow[d] + Vrow[d];
      s += x[t];
      ss = fmaf(x[t], x[t], ss);
    }
#pragma unroll
    for (int m = 1; m < 64; m <<= 1) {
      s  += __shfl_xor(s, m);
      ss += __shfl_xor(ss, m);
    }
    const float mu  = s * (1.f / 320.f);
    const float var = ss * (1.f / 320.f) - mu * mu;
    const float rs  = rsqrtf(var + LN_EPS);
#pragma unroll
    for (int t = 0; t < 5; ++t) {
      const int d = lane + t * 64;
      float hv = (x[t] - mu) * rs * g1[d] + be1[d];
      hv = hv > 0.f ? hv : SLOPE * hv;
      h1[p][d] = __float2bfloat16(hv);
    }
  }
  __syncthreads();

  // ---- Phase 2: GEMM2. A = h1 (64x320 LDS), B = W2T slice (80 cols).
  f32x4 acc[4][5];
#pragma unroll
  for (int mf = 0; mf < 4; ++mf)
#pragma unroll
    for (int nf = 0; nf < 5; ++nf)
      acc[mf][nf] = (f32x4){0.f, 0.f, 0.f, 0.f};

  const __hip_bfloat16* __restrict__ Bbase = W2T + (w * 80 + r16) * 320;

#pragma unroll
  for (int kk = 0; kk < 10; ++kk) {
    const int koff = kk * 32 + g * 8;
    bf16x8 a[4], b[5];
#pragma unroll
    for (int mf = 0; mf < 4; ++mf)
      a[mf] = *(const bf16x8*)&h1[mf * 16 + r16][koff];
#pragma unroll
    for (int nf = 0; nf < 5; ++nf)
      b[nf] = *(const bf16x8*)(Bbase + nf * 16 * 320 + koff);
#pragma unroll
    for (int mf = 0; mf < 4; ++mf)
#pragma unroll
      for (int nf = 0; nf < 5; ++nf)
        acc[mf][nf] = __builtin_amdgcn_mfma_f32_16x16x32_bf16(
            a[mf], b[nf], acc[mf][nf], 0, 0, 0);
  }

  // per-lane epilogue params for its 5 columns
  float b2c[5], g2c[5], be2c[5], w3c[5];
#pragma unroll
  for (int nf = 0; nf < 5; ++nf) {
    const int col = w * 80 + nf * 16 + r16;
    b2c[nf]  = b2[col];
    g2c[nf]  = g2[col];
    be2c[nf] = be2[col];
    w3c[nf]  = W3[col];
  }
  // h2_pre = acc + b2
#pragma unroll
  for (int nf = 0; nf < 5; ++nf)
#pragma unroll
    for (int mf = 0; mf < 4; ++mf)
#pragma unroll
      for (int r = 0; r < 4; ++r)
        acc[mf][nf][r] += b2c[nf];

  // ---- Phase 3: LN2 stats. row = mf*16 + g*4 + r, col = w*80 + nf*16 + r16
#pragma unroll
  for (int mf = 0; mf < 4; ++mf) {
#pragma unroll
    for (int r = 0; r < 4; ++r) {
      float s = 0.f, q = 0.f;
#pragma unroll
      for (int nf = 0; nf < 5; ++nf) {
        const float v = acc[mf][nf][r];
        s += v;
        q = fmaf(v, v, q);
      }
#pragma unroll
      for (int m = 1; m < 16; m <<= 1) {
        s += __shfl_xor(s, m);
        q += __shfl_xor(q, m);
      }
      if (r16 == 0) {
        const int row = mf * 16 + g * 4 + r;
        part[row][w][0] = s;
        part[row][w][1] = q;
      }
    }
  }
  __syncthreads();

  // ---- Phase 4: LN2 apply + leaky + dot with W3
#pragma unroll
  for (int mf = 0; mf < 4; ++mf) {
#pragma unroll
    for (int r = 0; r < 4; ++r) {
      const int row = mf * 16 + g * 4 + r;
      const float s = part[row][0][0] + part[row][1][0] +
                      part[row][2][0] + part[row][3][0];
      const float q = part[row][0][1] + part[row][1][1] +
                      part[row][2][1] + part[row][3][1];
      const float mu  = s * (1.f / 320.f);
      const float var = q * (1.f / 320.f) - mu * mu;
      const float rs  = rsqrtf(var + LN_EPS);
      float dsum = 0.f;
#pragma unroll
      for (int nf = 0; nf < 5; ++nf) {
        float v = (acc[mf][nf][r] - mu) * rs * g2c[nf] + be2c[nf];
        v = v > 0.f ? v : SLOPE * v;
        dsum = fmaf(v, w3c[nf], dsum);
      }
#pragma unroll
      for (int m = 1; m < 16; m <<= 1)
        dsum += __shfl_xor(dsum, m);
      if (r16 == 0)
        pdot[row][w] = dsum;
    }
  }
  __syncthreads();

  if (tid < 64) {
    const float tot = pdot[tid][0] + pdot[tid][1] + pdot[tid][2] +
                      pdot[tid][3] + b3[0];
    out[i * 512 + j0 + tid] = fabsf(tot);
  }
}

// ---------------------------------------------------------------------------
extern "C" void kernel_launch(void* const* d_in, const int* in_sizes, int n_in,
                              void* d_out, int out_size, void* d_ws, size_t ws_size,
                              hipStream_t stream) {
  const float* robot  = (const float*)d_in[0];
  const float* object = (const float*)d_in[1];
  const float* lang   = (const float*)d_in[2];
  const float* W1  = (const float*)d_in[3];
  const float* b1  = (const float*)d_in[4];
  const float* g1  = (const float*)d_in[5];
  const float* be1 = (const float*)d_in[6];
  const float* W2  = (const float*)d_in[7];
  const float* b2  = (const float*)d_in[8];
  const float* g2  = (const float*)d_in[9];
  const float* be2 = (const float*)d_in[10];
  const float* W3  = (const float*)d_in[11];
  const float* b3  = (const float*)d_in[12];
  float* out = (float*)d_out;

  float* U = (float*)d_ws;                        // 512*320 f32
  float* V = U + 512 * 320;                       // 512*320 f32
  __hip_bfloat16* W2T = (__hip_bfloat16*)(V + 512 * 320);  // 320*320 bf16

  precompute_uv<<<512, 320, 0, stream>>>(robot, object, lang, W1, b1, U, V);
  transpose_w2<<<320, 320, 0, stream>>>(W2, W2T);
  fused_main<<<dim3(512, 8), 256, 0, stream>>>(U, V, W2T, g1, be1, b2, g2,
                                               be2, W3, b3, out);
}